// Round 2
// baseline (1431.813 us; speedup 1.0000x reference)
//
#include <hip/hip_runtime.h>

#define IN_CH 128
#define HEADS 4
#define OUT_CH 32
#define HC 128  // HEADS*OUT_CH

__device__ __forceinline__ unsigned flip_f32(float x) {
  unsigned u = __float_as_uint(x);
  return (u & 0x80000000u) ? ~u : (u | 0x80000000u);
}
__device__ __forceinline__ float unflip_f32(unsigned k) {
  unsigned u = (k & 0x80000000u) ? (k ^ 0x80000000u) : ~k;
  return __uint_as_float(u);
}

// proj[N][128] = x[N][128] @ W[128][128]; 128x128 tile, 8x8 per-thread register block
__global__ __launch_bounds__(256) void gemm_xW(const float* __restrict__ x,
                                               const float* __restrict__ W,
                                               float* __restrict__ proj, int N) {
  __shared__ float xs[128][132];  // [k][row], padded
  __shared__ float ws[128][128];  // [k][col]
  const int tid = threadIdx.x;
  const int row0 = blockIdx.x * 128;

  {
    const float4* Wv = (const float4*)W;
    float4* wsv = (float4*)ws;
#pragma unroll
    for (int i = 0; i < 16; ++i) wsv[i * 256 + tid] = Wv[i * 256 + tid];
  }
  {
    const int r = tid >> 1;
    const int k0 = (tid & 1) * 64;
    const int grow = row0 + r;
    const bool valid = grow < N;
    const float4* src = (const float4*)(x + (size_t)grow * IN_CH + k0);
#pragma unroll
    for (int i = 0; i < 16; ++i) {
      float4 v = valid ? src[i] : make_float4(0.f, 0.f, 0.f, 0.f);
      const int k = k0 + i * 4;
      xs[k][r] = v.x; xs[k + 1][r] = v.y; xs[k + 2][r] = v.z; xs[k + 3][r] = v.w;
    }
  }
  __syncthreads();

  const int cg = tid & 15;
  const int rg = tid >> 4;
  float acc[8][8];
#pragma unroll
  for (int r = 0; r < 8; ++r)
#pragma unroll
    for (int c = 0; c < 8; ++c) acc[r][c] = 0.f;

#pragma unroll 4
  for (int k = 0; k < 128; ++k) {
    float4 a0 = *(const float4*)&xs[k][rg * 8];
    float4 a1 = *(const float4*)&xs[k][rg * 8 + 4];
    float4 b0 = *(const float4*)&ws[k][cg * 8];
    float4 b1 = *(const float4*)&ws[k][cg * 8 + 4];
    float xv[8] = {a0.x, a0.y, a0.z, a0.w, a1.x, a1.y, a1.z, a1.w};
    float wv[8] = {b0.x, b0.y, b0.z, b0.w, b1.x, b1.y, b1.z, b1.w};
#pragma unroll
    for (int r = 0; r < 8; ++r)
#pragma unroll
      for (int c = 0; c < 8; ++c) acc[r][c] += xv[r] * wv[c];
  }

#pragma unroll
  for (int r = 0; r < 8; ++r) {
    const int grow = row0 + rg * 8 + r;
    if (grow < N) {
      float4* dst = (float4*)(proj + (size_t)grow * HC + cg * 8);
      dst[0] = make_float4(acc[r][0], acc[r][1], acc[r][2], acc[r][3]);
      dst[1] = make_float4(acc[r][4], acc[r][5], acc[r][6], acc[r][7]);
    }
  }
}

// Pass 1: per-(edge,head) scores + global per-head max.
// 128 threads/edge (2 edges per 256-block), grid-strided so only 4 global
// atomicMax per block (~8k total on 4 addresses instead of 6.4M).
__global__ __launch_bounds__(256) void edge_score(const float* __restrict__ proj,
                                                  const int* __restrict__ erow,
                                                  const int* __restrict__ ecol,
                                                  const float* __restrict__ att,
                                                  float* __restrict__ scores,   // may be null
                                                  unsigned* __restrict__ headmax_key,
                                                  int E) {
  __shared__ unsigned blkmax[HEADS];
  const int tid = threadIdx.x;
  if (tid < HEADS) blkmax[tid] = 0u;  // ordered-key minimum
  __syncthreads();

  const int ch = tid & 127;
  const int h = ch >> 5;
  const int sub = tid >> 7;  // which edge of the pair
  const float av = att[ch];
  float lmax = -3.0e38f;

  for (int e = blockIdx.x * 2 + sub; e < E; e += gridDim.x * 2) {
    const int row = erow[e];
    const int col = ecol[e];
    const float sv = proj[(size_t)row * HC + ch];
    const float dv = proj[(size_t)col * HC + ch];
    const float xsum = sv + dv;
    const float t = 1.f - 2.f / (__expf(2.f * xsum) + 1.f);  // tanh
    float p = t * av;
#pragma unroll
    for (int m = 16; m >= 1; m >>= 1) p += __shfl_xor(p, m, 64);
    // all 32 lanes of the head-group now hold the full score p
    if (scores && (ch & 31) == 0) scores[(size_t)e * HEADS + h] = p;
    lmax = fmaxf(lmax, p);
  }
  if ((ch & 31) == 0) atomicMax(&blkmax[h], flip_f32(lmax));
  __syncthreads();
  if (tid < HEADS) atomicMax(&headmax_key[tid], blkmax[tid]);
}

// Pass 2: w = exp(s - M) in the reference's shifted domain, scatter-add.
template <bool HAVE_SCORES>
__global__ __launch_bounds__(256) void edge_apply(const float* __restrict__ proj,
                                                  const int* __restrict__ erow,
                                                  const int* __restrict__ ecol,
                                                  const float* __restrict__ att,
                                                  const float* __restrict__ scores,
                                                  const unsigned* __restrict__ headmax_key,
                                                  float* __restrict__ out,
                                                  float* __restrict__ norm, int E) {
  const int tid = threadIdx.x;
  const int e = blockIdx.x * 2 + (tid >> 7);
  if (e >= E) return;
  const int ch = tid & 127;
  const int h = ch >> 5;
  const float M = unflip_f32(headmax_key[h]);
  const int row = erow[e];
  const int col = ecol[e];
  const float sv = proj[(size_t)row * HC + ch];
  float s;
  if (HAVE_SCORES) {
    s = scores[(size_t)e * HEADS + h];
  } else {
    const float dv = proj[(size_t)col * HC + ch];
    const float t = 1.f - 2.f / (__expf(2.f * (sv + dv)) + 1.f);
    float p = t * att[ch];
#pragma unroll
    for (int m = 16; m >= 1; m >>= 1) p += __shfl_xor(p, m, 64);
    s = p;
  }
  const float w = __expf(s - M);
  unsafeAtomicAdd(&out[(size_t)col * HC + ch], sv * w);
  if ((ch & 31) == 0) unsafeAtomicAdd(&norm[(size_t)col * HEADS + h], w);
}

__global__ __launch_bounds__(256) void finalize(float* __restrict__ out,
                                                const float* __restrict__ norm, int N) {
  const int idx = blockIdx.x * blockDim.x + threadIdx.x;  // float4 index
  const int total = N * (HC / 4);
  if (idx >= total) return;
  const int base = idx * 4;
  const int node = base >> 7;
  const int h = (base >> 5) & 3;
  const float inv = 1.f / fmaxf(norm[node * HEADS + h], 1e-12f);
  float4 v = ((float4*)out)[idx];
  v.x *= inv; v.y *= inv; v.z *= inv; v.w *= inv;
  ((float4*)out)[idx] = v;
}

extern "C" void kernel_launch(void* const* d_in, const int* in_sizes, int n_in,
                              void* d_out, int out_size, void* d_ws, size_t ws_size,
                              hipStream_t stream) {
  const float* x    = (const float*)d_in[0];
  const int*   eidx = (const int*)d_in[1];   // [2][E]: first E = row(src), next E = col(dst)
  const float* W    = (const float*)d_in[2];
  const float* att  = (const float*)d_in[3];
  float* out = (float*)d_out;

  const int N = in_sizes[0] / IN_CH;
  const int E = in_sizes[1] / 2;

  // ws layout: proj | norm | headmax | scores(optional)
  float*    proj    = (float*)d_ws;
  float*    norm    = proj + (size_t)N * HC;
  unsigned* headmax = (unsigned*)(norm + (size_t)N * HEADS);
  float*    scores  = (float*)(headmax + 4);
  const size_t need_scores =
      ((size_t)N * HC + (size_t)N * HEADS + 1 /*4 uints*/) * 4 + (size_t)E * HEADS * 4 + 16;
  const bool have_scores = ws_size >= need_scores;

  hipMemsetAsync(out, 0, (size_t)out_size * sizeof(float), stream);
  hipMemsetAsync(norm, 0, (size_t)N * HEADS * sizeof(float), stream);
  hipMemsetAsync(headmax, 0, 4 * sizeof(unsigned), stream);  // ordered-key minimum

  gemm_xW<<<(N + 127) / 128, 256, 0, stream>>>(x, W, proj, N);
  edge_score<<<2048, 256, 0, stream>>>(proj, eidx, eidx + E, att,
                                       have_scores ? scores : nullptr, headmax, E);
  if (have_scores)
    edge_apply<true><<<(E + 1) / 2, 256, 0, stream>>>(proj, eidx, eidx + E, att, scores,
                                                      headmax, out, norm, E);
  else
    edge_apply<false><<<(E + 1) / 2, 256, 0, stream>>>(proj, eidx, eidx + E, att, scores,
                                                       headmax, out, norm, E);
  finalize<<<(N * (HC / 4) + 255) / 256, 256, 0, stream>>>(out, norm, N);
}